// Round 9
// baseline (122.987 us; speedup 1.0000x reference)
//
#include <hip/hip_runtime.h>
#include <math.h>

#define HDIM 1024
#define INVB (1 << 13)
#define SBIT (1 << 14)
#define OBIT (1 << 15)
#define SLOTS 10   // chunk = 32 compacted rows, capacity 320 adj-rows per b

// ---------------- K0: compacted adj-row list with mask bits -----------------
// grid 64 blocks (per b) x 512 threads.
// idxK: rows with adj=1, code = n | s<<14 | o<<15; padded to x32 with INVB.
__global__ __launch_bounds__(512) void k_prep(const int* __restrict__ adj,
                                              const int* __restrict__ sm,
                                              const int* __restrict__ om,
                                              int* __restrict__ idxK,
                                              int* __restrict__ cntKp) {
    __shared__ int cK[8];
    int b = blockIdx.x;
    int n = threadIdx.x;
    int wave = n >> 6, lane = n & 63;
    int idx = b * 512 + n;
    int a = adj[idx], s = sm[idx], o = om[idx];
    int predK = (a != 0);
    unsigned long long mK = __ballot(predK);
    if (lane == 0) cK[wave] = __popcll(mK);
    __syncthreads();
    int off = 0;
    for (int i = 0; i < wave; ++i) off += cK[i];
    unsigned long long lt = (1ull << lane) - 1ull;
    int pK = off + __popcll(mK & lt);
    if (predK) idxK[b * 512 + pK] = n | (s ? SBIT : 0) | (o ? OBIT : 0);
    if (n == 0) {
        int cnt = 0;
        for (int i = 0; i < 8; ++i) cnt += cK[i];
        int kp = (cnt + 31) & ~31;
        for (int i = cnt; i < kp; ++i) idxK[b * 512 + i] = INVB;
        cntKp[b] = kp;
    }
}

// ---------------- K1: fused score+exp -> e, and V-weight partials -----------
// grid 64*SLOTS blocks x 256 threads; chunk = 32 compacted adj rows.
// Phase 1: 4 waves x 8 rows -> e = exp(dot(K,Wk)), write e_out, stage weights.
// Phase 2: wave 0 compacts (s|o)-active rows; stream those V rows 8-deep.
__global__ __launch_bounds__(256) void k_fusedA(const float* __restrict__ Kmat,
                                                const float* __restrict__ V,
                                                const float* __restrict__ Wk,
                                                const int* __restrict__ idxK,
                                                const int* __restrict__ cntKp,
                                                float* __restrict__ e_out,
                                                float* __restrict__ p0,
                                                float* __restrict__ p1) {
    __shared__ int codeL[32];
    __shared__ float2 eso[32];
    __shared__ float2 cw[40];
    __shared__ int cn[40];
    __shared__ int s_cnz8;
    int b = blockIdx.x / SLOTS;
    int chunk = blockIdx.x - b * SLOTS;
    int tid = threadIdx.x, wave = tid >> 6, lane = tid & 63;
    int gb = b * 512;
    int start = chunk * 32;
    size_t pbase = ((size_t)(chunk * 64 + b)) * HDIM + tid * 4;

    if (start >= cntKp[b]) {                // inactive slot: zero the partial
        float4 z = {0.f, 0.f, 0.f, 0.f};
        *(float4*)(p0 + pbase) = z;
        *(float4*)(p1 + pbase) = z;
        return;
    }

    if (tid < 32) codeL[tid] = idxK[gb + start + tid];
    const float4* wk4 = (const float4*)Wk;
    float4 wk0 = wk4[lane], wk1 = wk4[64 + lane],
           wk2 = wk4[128 + lane], wk3 = wk4[192 + lane];
    __syncthreads();

    // ---- phase 1: 8 rows per wave, two at a time, 8 loads in flight --------
#pragma unroll
    for (int pp = 0; pp < 4; ++pp) {
        int rr = wave * 8 + pp * 2;
        int c0 = codeL[rr], c1 = codeL[rr + 1];
        int n0 = c0 & 511, n1 = c1 & 511;
        const float4* kp0 = (const float4*)(Kmat + (size_t)(gb + n0) * HDIM);
        const float4* kp1 = (const float4*)(Kmat + (size_t)(gb + n1) * HDIM);
        float4 a0 = kp0[lane],       a1 = kp0[64 + lane],
               a2 = kp0[128 + lane], a3 = kp0[192 + lane];
        float4 d0 = kp1[lane],       d1 = kp1[64 + lane],
               d2 = kp1[128 + lane], d3 = kp1[192 + lane];
        __builtin_amdgcn_sched_barrier(0);

        float s0 = 0.f, s1 = 0.f;
        s0 = fmaf(a0.x, wk0.x, s0); s0 = fmaf(a0.y, wk0.y, s0);
        s0 = fmaf(a0.z, wk0.z, s0); s0 = fmaf(a0.w, wk0.w, s0);
        s0 = fmaf(a1.x, wk1.x, s0); s0 = fmaf(a1.y, wk1.y, s0);
        s0 = fmaf(a1.z, wk1.z, s0); s0 = fmaf(a1.w, wk1.w, s0);
        s0 = fmaf(a2.x, wk2.x, s0); s0 = fmaf(a2.y, wk2.y, s0);
        s0 = fmaf(a2.z, wk2.z, s0); s0 = fmaf(a2.w, wk2.w, s0);
        s0 = fmaf(a3.x, wk3.x, s0); s0 = fmaf(a3.y, wk3.y, s0);
        s0 = fmaf(a3.z, wk3.z, s0); s0 = fmaf(a3.w, wk3.w, s0);
        s1 = fmaf(d0.x, wk0.x, s1); s1 = fmaf(d0.y, wk0.y, s1);
        s1 = fmaf(d0.z, wk0.z, s1); s1 = fmaf(d0.w, wk0.w, s1);
        s1 = fmaf(d1.x, wk1.x, s1); s1 = fmaf(d1.y, wk1.y, s1);
        s1 = fmaf(d1.z, wk1.z, s1); s1 = fmaf(d1.w, wk1.w, s1);
        s1 = fmaf(d2.x, wk2.x, s1); s1 = fmaf(d2.y, wk2.y, s1);
        s1 = fmaf(d2.z, wk2.z, s1); s1 = fmaf(d2.w, wk2.w, s1);
        s1 = fmaf(d3.x, wk3.x, s1); s1 = fmaf(d3.y, wk3.y, s1);
        s1 = fmaf(d3.z, wk3.z, s1); s1 = fmaf(d3.w, wk3.w, s1);

#pragma unroll
        for (int off = 32; off; off >>= 1) {
            s0 += __shfl_xor(s0, off);
            s1 += __shfl_xor(s1, off);
        }
        if (lane == 0) {
            float e0 = expf(s0), e1 = expf(s1);
            if (!(c0 & INVB)) e_out[gb + n0] = e0;
            if (!(c1 & INVB)) e_out[gb + n1] = e1;
            eso[rr]     = make_float2((c0 & SBIT) ? e0 : 0.f, (c0 & OBIT) ? e0 : 0.f);
            eso[rr + 1] = make_float2((c1 & SBIT) ? e1 : 0.f, (c1 & OBIT) ? e1 : 0.f);
        }
    }
    __syncthreads();

    // ---- compaction of (s|o)-active rows by wave 0 -------------------------
    if (wave == 0) {
        bool pred = (lane < 32) && ((codeL[lane] & (SBIT | OBIT)) != 0) &&
                    !(codeL[lane] & INVB);
        unsigned long long m = __ballot(pred);
        int cnz = __popcll(m);
        if (pred) {
            int pos = __popcll(m & ((1ull << lane) - 1ull));
            cn[pos] = codeL[lane] & 511;
            cw[pos] = eso[lane];
        }
        int cnz8 = (cnz + 7) & ~7;
        if (lane >= 32 && lane < 40) {
            int p = cnz + (lane - 32);
            if (p < cnz8) { cn[p] = 0; cw[p] = make_float2(0.f, 0.f); }
        }
        if (lane == 0) s_cnz8 = cnz8;
    }
    __syncthreads();

    // ---- phase 2: V-weight active rows, 8-deep batches ---------------------
    int cnz8 = s_cnz8;
    const float* Vb = V + (size_t)gb * HDIM;
    float4 a0 = {0.f, 0.f, 0.f, 0.f};
    float4 a1 = {0.f, 0.f, 0.f, 0.f};
    for (int g = 0; g < cnz8; g += 8) {
        int nn[8]; float2 ww[8];
#pragma unroll
        for (int i = 0; i < 8; ++i) { nn[i] = cn[g + i]; ww[i] = cw[g + i]; }
        float4 v[8];
#pragma unroll
        for (int i = 0; i < 8; ++i)
            v[i] = *((const float4*)(Vb + (size_t)nn[i] * HDIM) + tid);
        __builtin_amdgcn_sched_barrier(0);
#pragma unroll
        for (int i = 0; i < 8; ++i) {
            a0.x = fmaf(ww[i].x, v[i].x, a0.x); a0.y = fmaf(ww[i].x, v[i].y, a0.y);
            a0.z = fmaf(ww[i].x, v[i].z, a0.z); a0.w = fmaf(ww[i].x, v[i].w, a0.w);
            a1.x = fmaf(ww[i].y, v[i].x, a1.x); a1.y = fmaf(ww[i].y, v[i].y, a1.y);
            a1.z = fmaf(ww[i].y, v[i].z, a1.z); a1.w = fmaf(ww[i].y, v[i].w, a1.w);
        }
    }
    *(float4*)(p0 + pbase) = a0;
    *(float4*)(p1 + pbase) = a1;
}

// ---------------- K2: denom + attn_weight + u reduce+normalize --------------
// grid 64 blocks (per b) x 512 threads.
__global__ __launch_bounds__(512) void k_denomredu(const float* __restrict__ e,
                                                   const int* __restrict__ adj,
                                                   const float* __restrict__ p0,
                                                   const float* __restrict__ p1,
                                                   float* __restrict__ w_out,
                                                   float* __restrict__ u0,
                                                   float* __restrict__ u1) {
    __shared__ float red[8];
    int b = blockIdx.x;
    int tid = threadIdx.x;
    int wave = tid >> 6, lane = tid & 63;
    int idx = b * 512 + tid;

    float ev = adj[idx] ? e[idx] : 0.f;
    float t = ev;
#pragma unroll
    for (int off = 32; off; off >>= 1) t += __shfl_xor(t, off);
    if (lane == 0) red[wave] = t;
    __syncthreads();
    float tot = red[0];
#pragma unroll
    for (int i = 1; i < 8; ++i) tot += red[i];
    float inv = 1.f / tot;
    w_out[idx] = ev * inv;

    const float* p = (tid < 256) ? p0 : p1;
    float* u = (tid < 256) ? u0 : u1;
    int h4 = tid & 255;
    float4 a = {0.f, 0.f, 0.f, 0.f};
#pragma unroll
    for (int s = 0; s < SLOTS; ++s) {
        float4 v = *(const float4*)(p + ((size_t)(s * 64 + b)) * HDIM + h4 * 4);
        a.x += v.x; a.y += v.y; a.z += v.z; a.w += v.w;
    }
    a.x *= inv; a.y *= inv; a.z *= inv; a.w *= inv;
    *(float4*)(u + (size_t)b * HDIM + h4 * 4) = a;
}

// ---------------- K3: split-k GEMM, atomic k-reduction into out1 ------------
// out1[b][h] += sum_k u[b][k]*Wr[h][k]  (out1 pre-zeroed via memsetAsync).
// grid 256 blocks (ht*16+kc) x 256 threads. lane=b, wave owns 16 h rows.
__global__ __launch_bounds__(256) void k_out(const float* __restrict__ u0,
                                             const float* __restrict__ u1,
                                             const float* __restrict__ Wr0,
                                             const float* __restrict__ Wr1,
                                             float* __restrict__ out1) {
    __shared__ float lds[64 * 128];
    int tid = threadIdx.x;
    int ht = blockIdx.x >> 4;
    int kc = blockIdx.x & 15;
    const float* usrc = (kc < 8) ? u0 : u1;
    const float* wsrc = (kc < 8) ? Wr0 : Wr1;
    int koff = (kc & 7) * 128;
    int h0 = ht * 64;

    {
        int c4 = tid & 31;
        int r2 = tid >> 5;
#pragma unroll
        for (int i = 0; i < 8; ++i) {
            int row = i * 8 + r2;
            float4 v = *(const float4*)(usrc + (size_t)row * HDIM + koff + c4 * 4);
            *(float4*)&lds[row * 128 + ((c4 ^ (row & 7)) << 2)] = v;
        }
    }
    __syncthreads();

    int b = tid & 63;
    int wu = __builtin_amdgcn_readfirstlane(tid >> 6);
    int hbase = h0 + wu * 16;
    const float* wrow = wsrc + (size_t)hbase * HDIM + koff;

    float acc[16];
#pragma unroll
    for (int j = 0; j < 16; ++j) acc[j] = 0.f;

#pragma unroll 4
    for (int k4 = 0; k4 < 32; ++k4) {
        float4 uv = *(float4*)&lds[b * 128 + ((k4 ^ (b & 7)) << 2)];
#pragma unroll
        for (int j = 0; j < 16; ++j) {
            float4 wv = *(const float4*)(wrow + (size_t)j * HDIM + k4 * 4);
            acc[j] = fmaf(uv.x, wv.x, acc[j]);
            acc[j] = fmaf(uv.y, wv.y, acc[j]);
            acc[j] = fmaf(uv.z, wv.z, acc[j]);
            acc[j] = fmaf(uv.w, wv.w, acc[j]);
        }
    }
    float* dst = out1 + (size_t)b * HDIM + hbase;
#pragma unroll
    for (int j = 0; j < 16; ++j)
        unsafeAtomicAdd(dst + j, acc[j]);
}

extern "C" void kernel_launch(void* const* d_in, const int* in_sizes, int n_in,
                              void* d_out, int out_size, void* d_ws, size_t ws_size,
                              hipStream_t stream) {
    const float* Kmat  = (const float*)d_in[1];
    const float* V     = (const float*)d_in[2];
    const int*   adj   = (const int*)d_in[3];
    const int*   smask = (const int*)d_in[4];
    const int*   omask = (const int*)d_in[5];
    const float* Watt  = (const float*)d_in[6];
    const float* Wr0   = (const float*)d_in[8];
    const float* Wr1   = (const float*)d_in[9];
    float* out = (float*)d_out;
    float* ws  = (float*)d_ws;

    // ws layout (float offsets)
    float* e    = ws;                    //  64*512           = 32768
    int*   idxK = (int*)(ws + 32768);    //  64*512           = 32768
    int*   cKp  = (int*)(ws + 65536);    //  64 (pad 128)
    float* p0   = ws + 65664;            //  SLOTS*64*1024    = 655360
    float* p1   = ws + 721024;           //  SLOTS*64*1024    = 655360
    float* u0   = ws + 1376384;          //  64*1024          = 65536
    float* u1   = ws + 1441920;          //  64*1024          = 65536
    const float* Wk = Watt + HDIM;       // second half of W_att
    float* out1 = out + 32768;

    hipMemsetAsync(out1, 0, 64 * HDIM * sizeof(float), stream);
    k_prep     <<<        64, 512, 0, stream>>>(adj, smask, omask, idxK, cKp);
    k_fusedA   <<<64 * SLOTS, 256, 0, stream>>>(Kmat, V, Wk, idxK, cKp, e, p0, p1);
    k_denomredu<<<        64, 512, 0, stream>>>(e, adj, p0, p1, out, u0, u1);
    k_out      <<<       256, 256, 0, stream>>>(u0, u1, Wr0, Wr1, out1);
}

// Round 10
// 68.001 us; speedup vs baseline: 1.8086x; 1.8086x over previous
//
#include <hip/hip_runtime.h>
#include <math.h>

#define HDIM 1024
#define INVB (1 << 13)
#define SBIT (1 << 14)
#define OBIT (1 << 15)
#define SLOTS 10   // chunk = 32 compacted rows, capacity 320 adj-rows per b

// ---------------- K0: compacted adj-row list with mask bits -----------------
// grid 64 blocks (per b) x 512 threads.
// idxK: rows with adj=1, code = n | s<<14 | o<<15; padded to x32 with INVB.
__global__ __launch_bounds__(512) void k_prep(const int* __restrict__ adj,
                                              const int* __restrict__ sm,
                                              const int* __restrict__ om,
                                              int* __restrict__ idxK,
                                              int* __restrict__ cntKp) {
    __shared__ int cK[8];
    int b = blockIdx.x;
    int n = threadIdx.x;
    int wave = n >> 6, lane = n & 63;
    int idx = b * 512 + n;
    int a = adj[idx], s = sm[idx], o = om[idx];
    int predK = (a != 0);
    unsigned long long mK = __ballot(predK);
    if (lane == 0) cK[wave] = __popcll(mK);
    __syncthreads();
    int off = 0;
    for (int i = 0; i < wave; ++i) off += cK[i];
    unsigned long long lt = (1ull << lane) - 1ull;
    int pK = off + __popcll(mK & lt);
    if (predK) idxK[b * 512 + pK] = n | (s ? SBIT : 0) | (o ? OBIT : 0);
    if (n == 0) {
        int cnt = 0;
        for (int i = 0; i < 8; ++i) cnt += cK[i];
        int kp = (cnt + 31) & ~31;
        for (int i = cnt; i < kp; ++i) idxK[b * 512 + i] = INVB;
        cntKp[b] = kp;
    }
}

// ---------------- K1: fused score+exp -> e, and V-weight partials -----------
// grid 64*SLOTS blocks x 256 threads; chunk = 32 compacted adj rows.
// Phase 1: 4 waves x 8 rows -> e = exp(dot(K,Wk)), write e_out, stage weights.
// Phase 2: wave 0 compacts (s|o)-active rows; stream those V rows 8-deep.
__global__ __launch_bounds__(256) void k_fusedA(const float* __restrict__ Kmat,
                                                const float* __restrict__ V,
                                                const float* __restrict__ Wk,
                                                const int* __restrict__ idxK,
                                                const int* __restrict__ cntKp,
                                                float* __restrict__ e_out,
                                                float* __restrict__ p0,
                                                float* __restrict__ p1) {
    __shared__ int codeL[32];
    __shared__ float2 eso[32];
    __shared__ float2 cw[40];
    __shared__ int cn[40];
    __shared__ int s_cnz8;
    int b = blockIdx.x / SLOTS;
    int chunk = blockIdx.x - b * SLOTS;
    int tid = threadIdx.x, wave = tid >> 6, lane = tid & 63;
    int gb = b * 512;
    int start = chunk * 32;
    size_t pbase = ((size_t)(chunk * 64 + b)) * HDIM + tid * 4;

    if (start >= cntKp[b]) {                // inactive slot: zero the partial
        float4 z = {0.f, 0.f, 0.f, 0.f};
        *(float4*)(p0 + pbase) = z;
        *(float4*)(p1 + pbase) = z;
        return;
    }

    if (tid < 32) codeL[tid] = idxK[gb + start + tid];
    const float4* wk4 = (const float4*)Wk;
    float4 wk0 = wk4[lane], wk1 = wk4[64 + lane],
           wk2 = wk4[128 + lane], wk3 = wk4[192 + lane];
    __syncthreads();

    // ---- phase 1: 8 rows per wave, two at a time, 8 loads in flight --------
#pragma unroll
    for (int pp = 0; pp < 4; ++pp) {
        int rr = wave * 8 + pp * 2;
        int c0 = codeL[rr], c1 = codeL[rr + 1];
        int n0 = c0 & 511, n1 = c1 & 511;
        const float4* kp0 = (const float4*)(Kmat + (size_t)(gb + n0) * HDIM);
        const float4* kp1 = (const float4*)(Kmat + (size_t)(gb + n1) * HDIM);
        float4 a0 = kp0[lane],       a1 = kp0[64 + lane],
               a2 = kp0[128 + lane], a3 = kp0[192 + lane];
        float4 d0 = kp1[lane],       d1 = kp1[64 + lane],
               d2 = kp1[128 + lane], d3 = kp1[192 + lane];
        __builtin_amdgcn_sched_barrier(0);

        float s0 = 0.f, s1 = 0.f;
        s0 = fmaf(a0.x, wk0.x, s0); s0 = fmaf(a0.y, wk0.y, s0);
        s0 = fmaf(a0.z, wk0.z, s0); s0 = fmaf(a0.w, wk0.w, s0);
        s0 = fmaf(a1.x, wk1.x, s0); s0 = fmaf(a1.y, wk1.y, s0);
        s0 = fmaf(a1.z, wk1.z, s0); s0 = fmaf(a1.w, wk1.w, s0);
        s0 = fmaf(a2.x, wk2.x, s0); s0 = fmaf(a2.y, wk2.y, s0);
        s0 = fmaf(a2.z, wk2.z, s0); s0 = fmaf(a2.w, wk2.w, s0);
        s0 = fmaf(a3.x, wk3.x, s0); s0 = fmaf(a3.y, wk3.y, s0);
        s0 = fmaf(a3.z, wk3.z, s0); s0 = fmaf(a3.w, wk3.w, s0);
        s1 = fmaf(d0.x, wk0.x, s1); s1 = fmaf(d0.y, wk0.y, s1);
        s1 = fmaf(d0.z, wk0.z, s1); s1 = fmaf(d0.w, wk0.w, s1);
        s1 = fmaf(d1.x, wk1.x, s1); s1 = fmaf(d1.y, wk1.y, s1);
        s1 = fmaf(d1.z, wk1.z, s1); s1 = fmaf(d1.w, wk1.w, s1);
        s1 = fmaf(d2.x, wk2.x, s1); s1 = fmaf(d2.y, wk2.y, s1);
        s1 = fmaf(d2.z, wk2.z, s1); s1 = fmaf(d2.w, wk2.w, s1);
        s1 = fmaf(d3.x, wk3.x, s1); s1 = fmaf(d3.y, wk3.y, s1);
        s1 = fmaf(d3.z, wk3.z, s1); s1 = fmaf(d3.w, wk3.w, s1);

#pragma unroll
        for (int off = 32; off; off >>= 1) {
            s0 += __shfl_xor(s0, off);
            s1 += __shfl_xor(s1, off);
        }
        if (lane == 0) {
            float e0 = expf(s0), e1 = expf(s1);
            if (!(c0 & INVB)) e_out[gb + n0] = e0;
            if (!(c1 & INVB)) e_out[gb + n1] = e1;
            eso[rr]     = make_float2((c0 & SBIT) ? e0 : 0.f, (c0 & OBIT) ? e0 : 0.f);
            eso[rr + 1] = make_float2((c1 & SBIT) ? e1 : 0.f, (c1 & OBIT) ? e1 : 0.f);
        }
    }
    __syncthreads();

    // ---- compaction of (s|o)-active rows by wave 0 -------------------------
    if (wave == 0) {
        bool pred = (lane < 32) && ((codeL[lane] & (SBIT | OBIT)) != 0) &&
                    !(codeL[lane] & INVB);
        unsigned long long m = __ballot(pred);
        int cnz = __popcll(m);
        if (pred) {
            int pos = __popcll(m & ((1ull << lane) - 1ull));
            cn[pos] = codeL[lane] & 511;
            cw[pos] = eso[lane];
        }
        int cnz8 = (cnz + 7) & ~7;
        if (lane >= 32 && lane < 40) {
            int p = cnz + (lane - 32);
            if (p < cnz8) { cn[p] = 0; cw[p] = make_float2(0.f, 0.f); }
        }
        if (lane == 0) s_cnz8 = cnz8;
    }
    __syncthreads();

    // ---- phase 2: V-weight active rows, 8-deep batches ---------------------
    int cnz8 = s_cnz8;
    const float* Vb = V + (size_t)gb * HDIM;
    float4 a0 = {0.f, 0.f, 0.f, 0.f};
    float4 a1 = {0.f, 0.f, 0.f, 0.f};
    for (int g = 0; g < cnz8; g += 8) {
        int nn[8]; float2 ww[8];
#pragma unroll
        for (int i = 0; i < 8; ++i) { nn[i] = cn[g + i]; ww[i] = cw[g + i]; }
        float4 v[8];
#pragma unroll
        for (int i = 0; i < 8; ++i)
            v[i] = *((const float4*)(Vb + (size_t)nn[i] * HDIM) + tid);
        __builtin_amdgcn_sched_barrier(0);
#pragma unroll
        for (int i = 0; i < 8; ++i) {
            a0.x = fmaf(ww[i].x, v[i].x, a0.x); a0.y = fmaf(ww[i].x, v[i].y, a0.y);
            a0.z = fmaf(ww[i].x, v[i].z, a0.z); a0.w = fmaf(ww[i].x, v[i].w, a0.w);
            a1.x = fmaf(ww[i].y, v[i].x, a1.x); a1.y = fmaf(ww[i].y, v[i].y, a1.y);
            a1.z = fmaf(ww[i].y, v[i].z, a1.z); a1.w = fmaf(ww[i].y, v[i].w, a1.w);
        }
    }
    *(float4*)(p0 + pbase) = a0;
    *(float4*)(p1 + pbase) = a1;
}

// ---------------- K2: denom + attn_weight + u reduce+normalize --------------
// grid 64 blocks (per b) x 512 threads.
__global__ __launch_bounds__(512) void k_denomredu(const float* __restrict__ e,
                                                   const int* __restrict__ adj,
                                                   const float* __restrict__ p0,
                                                   const float* __restrict__ p1,
                                                   float* __restrict__ w_out,
                                                   float* __restrict__ u0,
                                                   float* __restrict__ u1) {
    __shared__ float red[8];
    int b = blockIdx.x;
    int tid = threadIdx.x;
    int wave = tid >> 6, lane = tid & 63;
    int idx = b * 512 + tid;

    float ev = adj[idx] ? e[idx] : 0.f;
    float t = ev;
#pragma unroll
    for (int off = 32; off; off >>= 1) t += __shfl_xor(t, off);
    if (lane == 0) red[wave] = t;
    __syncthreads();
    float tot = red[0];
#pragma unroll
    for (int i = 1; i < 8; ++i) tot += red[i];
    float inv = 1.f / tot;
    w_out[idx] = ev * inv;

    const float* p = (tid < 256) ? p0 : p1;
    float* u = (tid < 256) ? u0 : u1;
    int h4 = tid & 255;
    float4 a = {0.f, 0.f, 0.f, 0.f};
#pragma unroll
    for (int s = 0; s < SLOTS; ++s) {
        float4 v = *(const float4*)(p + ((size_t)(s * 64 + b)) * HDIM + h4 * 4);
        a.x += v.x; a.y += v.y; a.z += v.z; a.w += v.w;
    }
    a.x *= inv; a.y *= inv; a.z *= inv; a.w *= inv;
    *(float4*)(u + (size_t)b * HDIM + h4 * 4) = a;
}

// ---------------- K3: split-k GEMM partials: pOut[kc][h][b] -----------------
// out[b][h] = sum_k u0[b][k]*Wr0[h][k] + u1[b][k]*Wr1[h][k]
// grid 256 blocks (ht*16+kc) x 256 threads. lane=b, wave owns 16 h rows.
__global__ __launch_bounds__(256) void k_out(const float* __restrict__ u0,
                                             const float* __restrict__ u1,
                                             const float* __restrict__ Wr0,
                                             const float* __restrict__ Wr1,
                                             float* __restrict__ pOut) {
    __shared__ float lds[64 * 128];
    int tid = threadIdx.x;
    int ht = blockIdx.x >> 4;
    int kc = blockIdx.x & 15;
    const float* usrc = (kc < 8) ? u0 : u1;
    const float* wsrc = (kc < 8) ? Wr0 : Wr1;
    int koff = (kc & 7) * 128;
    int h0 = ht * 64;

    {
        int c4 = tid & 31;
        int r2 = tid >> 5;
#pragma unroll
        for (int i = 0; i < 8; ++i) {
            int row = i * 8 + r2;
            float4 v = *(const float4*)(usrc + (size_t)row * HDIM + koff + c4 * 4);
            *(float4*)&lds[row * 128 + ((c4 ^ (row & 7)) << 2)] = v;
        }
    }
    __syncthreads();

    int b = tid & 63;
    int wu = __builtin_amdgcn_readfirstlane(tid >> 6);
    int hbase = h0 + wu * 16;
    const float* wrow = wsrc + (size_t)hbase * HDIM + koff;

    float acc[16];
#pragma unroll
    for (int j = 0; j < 16; ++j) acc[j] = 0.f;

#pragma unroll 4
    for (int k4 = 0; k4 < 32; ++k4) {
        float4 uv = *(float4*)&lds[b * 128 + ((k4 ^ (b & 7)) << 2)];
#pragma unroll
        for (int j = 0; j < 16; ++j) {
            float4 wv = *(const float4*)(wrow + (size_t)j * HDIM + k4 * 4);
            acc[j] = fmaf(uv.x, wv.x, acc[j]);
            acc[j] = fmaf(uv.y, wv.y, acc[j]);
            acc[j] = fmaf(uv.z, wv.z, acc[j]);
            acc[j] = fmaf(uv.w, wv.w, acc[j]);
        }
    }
#pragma unroll
    for (int j = 0; j < 16; ++j)
        pOut[((size_t)kc * HDIM + hbase + j) * 64 + b] = acc[j];
}

// ---------------- K4: reduce 16 k-chunks -> attn_sum[b][h] ------------------
// grid 256 blocks x 256 threads (4 h x 64 b per block).
__global__ __launch_bounds__(256) void k_redout(const float* __restrict__ pOut,
                                                float* __restrict__ out1) {
    int tid = threadIdx.x;
    int b = tid & 63;
    int h = blockIdx.x * 4 + (tid >> 6);
    float acc = 0.f;
#pragma unroll
    for (int kc = 0; kc < 16; ++kc)
        acc += pOut[((size_t)kc * HDIM + h) * 64 + b];
    out1[(size_t)b * HDIM + h] = acc;
}

extern "C" void kernel_launch(void* const* d_in, const int* in_sizes, int n_in,
                              void* d_out, int out_size, void* d_ws, size_t ws_size,
                              hipStream_t stream) {
    const float* Kmat  = (const float*)d_in[1];
    const float* V     = (const float*)d_in[2];
    const int*   adj   = (const int*)d_in[3];
    const int*   smask = (const int*)d_in[4];
    const int*   omask = (const int*)d_in[5];
    const float* Watt  = (const float*)d_in[6];
    const float* Wr0   = (const float*)d_in[8];
    const float* Wr1   = (const float*)d_in[9];
    float* out = (float*)d_out;
    float* ws  = (float*)d_ws;

    // ws layout (float offsets)
    float* e    = ws;                    //  64*512           = 32768
    int*   idxK = (int*)(ws + 32768);    //  64*512           = 32768
    int*   cKp  = (int*)(ws + 65536);    //  64 (pad 128)
    float* p0   = ws + 65664;            //  SLOTS*64*1024    = 655360
    float* p1   = ws + 721024;           //  SLOTS*64*1024    = 655360
    float* u0   = ws + 1376384;          //  64*1024          = 65536
    float* u1   = ws + 1441920;          //  64*1024          = 65536
    float* pOut = ws + 1507456;          //  16*1024*64       = 1048576
    const float* Wk = Watt + HDIM;       // second half of W_att

    k_prep     <<<        64, 512, 0, stream>>>(adj, smask, omask, idxK, cKp);
    k_fusedA   <<<64 * SLOTS, 256, 0, stream>>>(Kmat, V, Wk, idxK, cKp, e, p0, p1);
    k_denomredu<<<        64, 512, 0, stream>>>(e, adj, p0, p1, out, u0, u1);
    k_out      <<<       256, 256, 0, stream>>>(u0, u1, Wr0, Wr1, pOut);
    k_redout   <<<       256, 256, 0, stream>>>(pOut, out + 32768);
}